// Round 7
// baseline (188.277 us; speedup 1.0000x reference)
//
#include <hip/hip_runtime.h>
#include <hip/hip_bf16.h>
#include <math.h>

#define N 4096
#define K 2048
#define NC 32
#define MARGIN 0.3f
#define MAXTILES 1024
#define GRID_G 1024   // gemm blocks, 1 wave each

typedef float f32x4 __attribute__((ext_vector_type(4)));
typedef __bf16 bf16x8 __attribute__((ext_vector_type(8)));

__device__ __forceinline__ int imin(int a, int b) { return a < b ? a : b; }

// ---------------------------------------------------------------------------
// Kernel 0: planner. Builds class lists + nonzero list in LDS, then emits
// 64x64 tiles with RESOLVED original-row ids (128 ints per tile).
// tmeta bit0 = diag (ap/max) vs cross (an/min); bit1 = also reduce col side.
// Diag: per class, upper-triangle subtiles. Cross: class0 x nonzero.
// Clamped duplicate rows are real candidates -> no-ops under max/min.
// ---------------------------------------------------------------------------
__global__ __launch_bounds__(256) void plan_kernel(
    const int* __restrict__ tg, int* __restrict__ flag, int* __restrict__ done,
    int* __restrict__ Tp, int* __restrict__ tmeta, int* __restrict__ trows) {
  __shared__ int h[NC], off_[NC], cur[NC], stb[NC + 1];
  __shared__ int lcls[N];   // 16 KiB: rows grouped by class
  __shared__ int lnz[N];    // 16 KiB: nonzero-class rows
  __shared__ int ncur;
  int t = threadIdx.x;
  if (t < NC) h[t] = 0;
  if (t == 0) ncur = 0;
  __syncthreads();
  for (int i = t; i < N; i += 256) atomicAdd(&h[tg[i]], 1);
  __syncthreads();
  if (t == 0) {
    int acc = 0;
    for (int c = 0; c < NC; c++) { off_[c] = acc; cur[c] = acc; acc += h[c]; }
  }
  __syncthreads();
  for (int i = t; i < N; i += 256) {
    int c = tg[i];
    int p = atomicAdd(&cur[c], 1);
    lcls[p] = i;
    if (c != 0) { int q = atomicAdd(&ncur, 1); lnz[q] = i; }
  }
  __syncthreads();
  if (t == 0) {
    int tacc = 0;
    for (int c = 0; c < NC; c++) {
      stb[c] = tacc;
      int tt = (h[c] + 63) >> 6;
      tacc += (tt * (tt + 1)) >> 1;
    }
    stb[NC] = tacc;
    int n0 = h[0], nz = N - n0;
    int T = tacc + ((n0 > 0 && nz > 0) ? ((n0 + 63) >> 6) * ((nz + 63) >> 6) : 0);
    Tp[0] = imin(T, MAXTILES);
    flag[0] = (tg[0] == 0) ? (nz > 0) : (n0 > 0);
    done[0] = 0;
  }
  __syncthreads();
  // diag tiles: one thread per class
  if (t < NC && h[t] > 0) {
    int n = h[t], o = off_[t], tt = (n + 63) >> 6, idx = stb[t];
    for (int si = 0; si < tt; si++)
      for (int sj = si; sj < tt; sj++) {
        if (idx < MAXTILES) {
          tmeta[idx] = 1 | ((si < sj) ? 2 : 0);
          int* rw = trows + idx * 128;
          for (int r = 0; r < 64; r++) {
            rw[r]      = lcls[o + imin(si * 64 + r, n - 1)];
            rw[64 + r] = lcls[o + imin(sj * 64 + r, n - 1)];
          }
        }
        idx++;
      }
  }
  // cross tiles: parallel over threads
  {
    int n0 = h[0], nz = N - n0;
    if (n0 > 0 && nz > 0) {
      int t0b = (n0 + 63) >> 6, tzb = (nz + 63) >> 6, base = stb[NC];
      int o0 = off_[0];
      for (int k2 = t; k2 < t0b * tzb; k2 += 256) {
        int si = k2 / tzb, sj = k2 - si * tzb, idx = base + k2;
        if (idx < MAXTILES) {
          tmeta[idx] = 2;  // cross: min, both sides
          int* rw = trows + idx * 128;
          for (int r = 0; r < 64; r++) {
            rw[r]      = lcls[o0 + imin(si * 64 + r, n0 - 1)];
            rw[64 + r] = lnz[imin(sj * 64 + r, nz - 1)];
          }
        }
      }
    }
  }
}

// ---------------------------------------------------------------------------
// Kernel 1: fp32 -> bf16 convert (original row order, pure stream) +
// sum-of-squares + ap/an init. One block per row.
// ---------------------------------------------------------------------------
__global__ __launch_bounds__(256) void convert_kernel(
    const float* __restrict__ X, __bf16* __restrict__ Xb,
    float* __restrict__ sq, unsigned int* __restrict__ ap,
    unsigned int* __restrict__ an) {
  int row = blockIdx.x, t = threadIdx.x;
  const float* xr = X + (size_t)row * K;
  float4 v0 = ((const float4*)xr)[t * 2 + 0];
  float4 v1 = ((const float4*)xr)[t * 2 + 1];
  float s = v0.x * v0.x + v0.y * v0.y + v0.z * v0.z + v0.w * v0.w +
            v1.x * v1.x + v1.y * v1.y + v1.z * v1.z + v1.w * v1.w;
  bf16x8 b;
  b[0] = (__bf16)v0.x; b[1] = (__bf16)v0.y; b[2] = (__bf16)v0.z; b[3] = (__bf16)v0.w;
  b[4] = (__bf16)v1.x; b[5] = (__bf16)v1.y; b[6] = (__bf16)v1.z; b[7] = (__bf16)v1.w;
  ((bf16x8*)(Xb + (size_t)row * K))[t] = b;
  #pragma unroll
  for (int m = 32; m; m >>= 1) s += __shfl_xor(s, m);
  __shared__ float wred[4];
  if ((t & 63) == 0) wred[t >> 6] = s;
  __syncthreads();
  if (t == 0) {
    sq[row] = wred[0] + wred[1] + wred[2] + wred[3];
    ap[row] = 0u;           // identity for max of non-negative
    an[row] = 0x7f800000u;  // +inf
  }
}

// ---------------------------------------------------------------------------
// Kernel 2: register-only MFMA. One WAVE per (tile, half): 32x64 strip x
// full K. A/B fragments loaded directly global->VGPR (dwordx4, immediate
// k-offsets, no LDS, no barriers). Epilogue reduces d^2, sqrt late, atomics
// into original-row-space ap/an. Ticket -> final loss.
// ---------------------------------------------------------------------------
__global__ __launch_bounds__(64) void gemm_kernel(
    const __bf16* __restrict__ Xb, const float* __restrict__ sq,
    const int* __restrict__ Tp, const int* __restrict__ tmeta,
    const int* __restrict__ trows, const int* __restrict__ flag,
    int* __restrict__ done, unsigned int* __restrict__ ap,
    unsigned int* __restrict__ an, float* __restrict__ out) {
  int t = threadIdx.x;          // one wave
  int quad = t >> 4, lr = t & 15;
  int M = Tp[0] * 2;

  for (int m = blockIdx.x; m < M; m += GRID_G) {
    int tid = m >> 1, half = m & 1;
    int meta = tmeta[tid];
    bool diag = (meta & 1) != 0, colside = (meta & 2) != 0;
    const int* rw = trows + tid * 128;

    // Fragment rows: A (strip rows), B (tile cols); layout m=lane&15.
    int arow0 = rw[half * 32 + lr];
    int arow1 = rw[half * 32 + 16 + lr];
    int brow[4];
    #pragma unroll
    for (int tj = 0; tj < 4; tj++) brow[tj] = rw[64 + tj * 16 + lr];

    const char* pa0 = (const char*)Xb + (size_t)arow0 * 4096 + quad * 16;
    const char* pa1 = (const char*)Xb + (size_t)arow1 * 4096 + quad * 16;
    const char* pb0 = (const char*)Xb + (size_t)brow[0] * 4096 + quad * 16;
    const char* pb1 = (const char*)Xb + (size_t)brow[1] * 4096 + quad * 16;
    const char* pb2 = (const char*)Xb + (size_t)brow[2] * 4096 + quad * 16;
    const char* pb3 = (const char*)Xb + (size_t)brow[3] * 4096 + quad * 16;

    f32x4 acc[2][4];
    #pragma unroll
    for (int a = 0; a < 2; a++)
      #pragma unroll
      for (int c = 0; c < 4; c++) acc[a][c] = (f32x4)0.f;

    // K loop: 64 chunks of 32 elements; byte offset c*64 (imm, max 4032).
    #pragma unroll
    for (int c = 0; c < 64; c++) {
      bf16x8 a0 = *(const bf16x8*)(pa0 + c * 64);
      bf16x8 a1 = *(const bf16x8*)(pa1 + c * 64);
      bf16x8 b0 = *(const bf16x8*)(pb0 + c * 64);
      bf16x8 b1 = *(const bf16x8*)(pb1 + c * 64);
      bf16x8 b2 = *(const bf16x8*)(pb2 + c * 64);
      bf16x8 b3 = *(const bf16x8*)(pb3 + c * 64);
      acc[0][0] = __builtin_amdgcn_mfma_f32_16x16x32_bf16(a0, b0, acc[0][0], 0, 0, 0);
      acc[0][1] = __builtin_amdgcn_mfma_f32_16x16x32_bf16(a0, b1, acc[0][1], 0, 0, 0);
      acc[0][2] = __builtin_amdgcn_mfma_f32_16x16x32_bf16(a0, b2, acc[0][2], 0, 0, 0);
      acc[0][3] = __builtin_amdgcn_mfma_f32_16x16x32_bf16(a0, b3, acc[0][3], 0, 0, 0);
      acc[1][0] = __builtin_amdgcn_mfma_f32_16x16x32_bf16(a1, b0, acc[1][0], 0, 0, 0);
      acc[1][1] = __builtin_amdgcn_mfma_f32_16x16x32_bf16(a1, b1, acc[1][1], 0, 0, 0);
      acc[1][2] = __builtin_amdgcn_mfma_f32_16x16x32_bf16(a1, b2, acc[1][2], 0, 0, 0);
      acc[1][3] = __builtin_amdgcn_mfma_f32_16x16x32_bf16(a1, b3, acc[1][3], 0, 0, 0);
    }

    // Epilogue. C/D: col j = tj*16 + (lane&15), row i = ti*16 + quad*4 + r.
    float sqj[4];
    #pragma unroll
    for (int tj = 0; tj < 4; tj++) sqj[tj] = sq[brow[tj]];

    float cred[4];
    #pragma unroll
    for (int tj = 0; tj < 4; tj++) cred[tj] = diag ? 0.f : INFINITY;

    #pragma unroll
    for (int ti = 0; ti < 2; ti++) {
      #pragma unroll
      for (int r = 0; r < 4; r++) {
        int iorig = rw[half * 32 + ti * 16 + quad * 4 + r];
        float sqi = sq[iorig];
        float v = diag ? 0.f : INFINITY;
        #pragma unroll
        for (int tj = 0; tj < 4; tj++) {
          float d2 = fmaxf(sqi + sqj[tj] - 2.f * acc[ti][tj][r], 1e-12f);
          v = diag ? fmaxf(v, d2) : fminf(v, d2);
          cred[tj] = diag ? fmaxf(cred[tj], d2) : fminf(cred[tj], d2);
        }
        #pragma unroll
        for (int mm = 1; mm < 16; mm <<= 1) {
          float o = __shfl_xor(v, mm);
          v = diag ? fmaxf(v, o) : fminf(v, o);
        }
        if (lr == 0) {
          unsigned int u = __float_as_uint(sqrtf(v));
          if (diag) atomicMax(ap + iorig, u);
          else      atomicMin(an + iorig, u);
        }
      }
    }
    if (colside) {
      #pragma unroll
      for (int tj = 0; tj < 4; tj++) {
        float v = cred[tj];
        float o = __shfl_xor(v, 16);
        v = diag ? fmaxf(v, o) : fminf(v, o);
        o = __shfl_xor(v, 32);
        v = diag ? fmaxf(v, o) : fminf(v, o);
        if (quad == 0) {
          unsigned int u = __float_as_uint(sqrtf(v));
          if (diag) atomicMax(ap + brow[tj], u);
          else      atomicMin(an + brow[tj], u);
        }
      }
    }
  }

  // ---- last-block ticket: final loss reduction (single wave) ------------
  int lastv = 0;
  if (t == 0) {
    __threadfence();
    int ticket = __hip_atomic_fetch_add(done, 1, __ATOMIC_ACQ_REL,
                                        __HIP_MEMORY_SCOPE_AGENT);
    lastv = (ticket == GRID_G - 1);
  }
  lastv = __shfl(lastv, 0);
  if (lastv) {
    int has = flag[0];
    float s = 0.f;
    for (int i = t; i < N; i += 64) {
      unsigned int au = __hip_atomic_load(ap + i, __ATOMIC_RELAXED,
                                          __HIP_MEMORY_SCOPE_AGENT);
      unsigned int nu = __hip_atomic_load(an + i, __ATOMIC_RELAXED,
                                          __HIP_MEMORY_SCOPE_AGENT);
      float a = __uint_as_float(au);
      float bb = has ? __uint_as_float(nu) : 0.f;
      s += fmaxf(a - bb + MARGIN, 0.f);
    }
    #pragma unroll
    for (int mm = 32; mm; mm >>= 1) s += __shfl_xor(s, mm);
    if (t == 0) out[0] = s / (float)N;
  }
}

// ---------------------------------------------------------------------------
extern "C" void kernel_launch(void* const* d_in, const int* in_sizes, int n_in,
                              void* d_out, int out_size, void* d_ws,
                              size_t ws_size, hipStream_t stream) {
  const float* X = (const float*)d_in[0];
  const int* tg = (const int*)d_in[1];
  float* out = (float*)d_out;

  char* ws = (char*)d_ws;
  __bf16* Xb = (__bf16*)ws;
  size_t o = (size_t)N * K * 2;
  float* sq = (float*)(ws + o); o += (size_t)N * 4;
  unsigned int* ap = (unsigned int*)(ws + o); o += (size_t)N * 4;
  unsigned int* an = (unsigned int*)(ws + o); o += (size_t)N * 4;
  int* flag = (int*)(ws + o); o += 4;
  int* done = (int*)(ws + o); o += 4;
  int* Tp = (int*)(ws + o); o += 4;
  o = (o + 255) & ~(size_t)255;
  int* tmeta = (int*)(ws + o); o += (size_t)MAXTILES * 4;
  int* trows = (int*)(ws + o); o += (size_t)MAXTILES * 128 * 4;

  plan_kernel<<<1, 256, 0, stream>>>(tg, flag, done, Tp, tmeta, trows);
  convert_kernel<<<N, 256, 0, stream>>>(X, Xb, sq, ap, an);
  gemm_kernel<<<GRID_G, 64, 0, stream>>>(Xb, sq, Tp, tmeta, trows, flag,
                                         done, ap, an, out);
}